// Round 1
// baseline (2240.387 us; speedup 1.0000x reference)
//
#include <hip/hip_runtime.h>
#include <hip/hip_bf16.h>

// Problem constants
#define S 2048
#define D 768
#define H 12
#define HD 64
#define FF 3072
#define NL 6
#define WIN 128
#define PADIDX 1

typedef __hip_bfloat16 bf16;
typedef __attribute__((ext_vector_type(8))) __bf16 bf16x8;
typedef __attribute__((ext_vector_type(4))) float f32x4;
typedef __attribute__((ext_vector_type(8))) unsigned short u16x8;

__device__ __forceinline__ float bf2f(unsigned short u) {
    union { unsigned int i; float f; } c; c.i = ((unsigned int)u) << 16; return c.f;
}

// async global->LDS, 16B per lane. LDS base must be wave-uniform.
__device__ __forceinline__ void g2l16(const bf16* g, bf16* l) {
    __builtin_amdgcn_global_load_lds((__attribute__((address_space(1))) void*)(g),
                                     (__attribute__((address_space(3))) void*)(l), 16, 0, 0);
}

// ---------------- positions (fairseq make_positions) ----------------
__global__ void positions_kernel(const int* __restrict__ tokens, int* __restrict__ positions) {
    __shared__ int sums[256];
    int t = threadIdx.x;
    int np[8]; int loc = 0;
    for (int i = 0; i < 8; i++) { np[i] = (tokens[t * 8 + i] != PADIDX) ? 1 : 0; loc += np[i]; }
    sums[t] = loc;
    __syncthreads();
    for (int off = 1; off < 256; off <<= 1) {
        int u = (t >= off) ? sums[t - off] : 0;
        __syncthreads();
        sums[t] += u;
        __syncthreads();
    }
    int run = (t > 0) ? sums[t - 1] : 0;
    for (int i = 0; i < 8; i++) {
        run += np[i];
        positions[t * 8 + i] = np[i] ? (PADIDX + run) : PADIDX;
    }
}

// ---------------- embedding ----------------
__global__ void embed_kernel(const int* __restrict__ tokens, const int* __restrict__ seg,
                             const int* __restrict__ positions,
                             const float* __restrict__ emb, const float* __restrict__ pemb,
                             const float* __restrict__ semb,
                             float* __restrict__ h, bf16* __restrict__ h_bf) {
    int s = blockIdx.x, t = threadIdx.x;
    int tok = tokens[s];
    int pos = positions[s];
    int sg = seg[s];
    bool pad = (tok == PADIDX);
    for (int i = 0; i < 3; i++) {
        int c = t + i * 256;
        float val = emb[(size_t)tok * D + c] + pemb[(size_t)pos * D + c] + semb[(size_t)sg * D + c];
        if (pad) val = 0.0f;
        h[(size_t)s * D + c] = val;
        h_bf[(size_t)s * D + c] = __float2bfloat16(val);
    }
}

// ---------------- fp32 [K,N] -> bf16 [N,K] transpose+convert ----------------
__global__ void transpose_convert(const float* __restrict__ src, bf16* __restrict__ dst,
                                  int K, int N, long srcLS, long dstLS) {
    src += (long)blockIdx.z * srcLS;
    dst += (long)blockIdx.z * dstLS;
    __shared__ float tile[64][65];
    int k0 = blockIdx.x * 64, n0 = blockIdx.y * 64;
    int t = threadIdx.x;
    for (int i = t; i < 4096; i += 256) {
        int r = i >> 6, c = i & 63;
        tile[r][c] = src[(long)(k0 + r) * N + n0 + c];
    }
    __syncthreads();
    for (int i = t; i < 4096; i += 256) {
        int r = i >> 6, c = i & 63;
        dst[(long)(n0 + r) * K + k0 + c] = __float2bfloat16(tile[c][r]);
    }
}

// ---------------- GEMM: C[M,N] = A[M,K] @ Bt[N,K]^T (+epilogue) ----------------
// MODE 0: qkv  -> (acc + bias{q,k,v}[col]) * (col<768 ? 0.125 : 1), bf16 out
// MODE 1: bias -> acc + bias0[col], fp32 out
// MODE 2: ff1  -> relu(acc + bias0[col]), bf16 out
template <int MODE>
__global__ __launch_bounds__(256) void gemm_kernel(
    const bf16* __restrict__ A, const bf16* __restrict__ Bt,
    const float* __restrict__ bias0, const float* __restrict__ bias1, const float* __restrict__ bias2,
    float* __restrict__ outF, bf16* __restrict__ outB, int M, int N, int K) {
    __shared__ __align__(16) bf16 As[128 * 32];
    __shared__ __align__(16) bf16 Bs[128 * 32];
    int t = threadIdx.x;
    int lane = t & 63, w = t >> 6;
    int m0 = blockIdx.x * 128, n0 = blockIdx.y * 128;
    int wm = (w & 1) * 64, wn = (w >> 1) * 64;
    int qd = lane >> 4, l16 = lane & 15;

    f32x4 acc[4][4] = {};

    int ll0 = t, ll1 = t + 256;
    const bf16* Ag0 = A + (size_t)(m0 + (ll0 >> 2)) * K + (ll0 & 3) * 8;
    const bf16* Ag1 = A + (size_t)(m0 + (ll1 >> 2)) * K + (ll1 & 3) * 8;
    const bf16* Bg0 = Bt + (size_t)(n0 + (ll0 >> 2)) * K + (ll0 & 3) * 8;
    const bf16* Bg1 = Bt + (size_t)(n0 + (ll1 >> 2)) * K + (ll1 & 3) * 8;
    bf16* Al0 = As + (size_t)(t & ~63) * 8;
    bf16* Al1 = As + (size_t)(256 + (t & ~63)) * 8;
    bf16* Bl0 = Bs + (size_t)(t & ~63) * 8;
    bf16* Bl1 = Bs + (size_t)(256 + (t & ~63)) * 8;

    int nkt = K >> 5;
    for (int kt = 0; kt < nkt; ++kt) {
        int ko = kt * 32;
        g2l16(Ag0 + ko, Al0);
        g2l16(Ag1 + ko, Al1);
        g2l16(Bg0 + ko, Bl0);
        g2l16(Bg1 + ko, Bl1);
        __syncthreads();
        bf16x8 aF[4], bF[4];
#pragma unroll
        for (int mi = 0; mi < 4; mi++) aF[mi] = *(const bf16x8*)&As[(wm + mi * 16 + l16) * 32 + qd * 8];
#pragma unroll
        for (int ni = 0; ni < 4; ni++) bF[ni] = *(const bf16x8*)&Bs[(wn + ni * 16 + l16) * 32 + qd * 8];
#pragma unroll
        for (int mi = 0; mi < 4; mi++)
#pragma unroll
            for (int ni = 0; ni < 4; ni++)
                acc[mi][ni] = __builtin_amdgcn_mfma_f32_16x16x32_bf16(aF[mi], bF[ni], acc[mi][ni], 0, 0, 0);
        __syncthreads();
    }

#pragma unroll
    for (int ni = 0; ni < 4; ni++) {
        int col = n0 + wn + ni * 16 + l16;
        float bb;
        if (MODE == 0) bb = (col < 768) ? bias0[col] : ((col < 1536) ? bias1[col - 768] : bias2[col - 1536]);
        else bb = bias0[col];
#pragma unroll
        for (int mi = 0; mi < 4; mi++) {
            int row = m0 + wm + mi * 16 + qd * 4;
#pragma unroll
            for (int r = 0; r < 4; r++) {
                float v = acc[mi][ni][r] + bb;
                if (MODE == 0) {
                    if (col < 768) v *= 0.125f;  // 1/sqrt(64)
                    outB[(size_t)(row + r) * N + col] = __float2bfloat16(v);
                } else if (MODE == 1) {
                    outF[(size_t)(row + r) * N + col] = v;
                } else {
                    v = fmaxf(v, 0.0f);
                    outB[(size_t)(row + r) * N + col] = __float2bfloat16(v);
                }
            }
        }
    }
}

// ---------------- windowed attention, one wave per (query, head) ----------------
// qkv: [S, 2304] bf16 (q|k|v); out: [S, 768] bf16
__global__ __launch_bounds__(64) void attn_kernel(const bf16* __restrict__ qkv,
                                                  const int* __restrict__ tokens,
                                                  const float* __restrict__ relb,
                                                  bf16* __restrict__ out) {
    int s = blockIdx.x;
    int hd = blockIdx.y;
    int lane = threadIdx.x;
    __shared__ float q_s[64];
    __shared__ float p_s[260];

    q_s[lane] = __bfloat162float(qkv[(size_t)s * 2304 + hd * 64 + lane]);
    __syncthreads();

    int klo = max(0, s - WIN), khi = min(S - 1, s + WIN);
    int nk = khi - klo + 1;

    float scores[5];
    float smax = -1e38f;
#pragma unroll
    for (int c = 0; c < 5; c++) {
        int ki = c * 64 + lane;
        float sc = -1e38f;
        if (ki < nk) {
            int key = klo + ki;
            const unsigned short* kr = (const unsigned short*)(qkv + (size_t)key * 2304 + 768 + hd * 64);
            float d = 0.0f;
#pragma unroll
            for (int j8 = 0; j8 < 8; j8++) {
                u16x8 kv = *(const u16x8*)(kr + j8 * 8);
#pragma unroll
                for (int u = 0; u < 8; u++) d += q_s[j8 * 8 + u] * bf2f(kv[u]);
            }
            // relative position bucket (exact integer thresholds; matches f32 ref)
            int ni = s - key;           // n = -rp, rp = key - s
            int ret = 0;
            if (ni < 0) { ret = 16; ni = -ni; }
            int val;
            if (ni < 8) val = ni;
            else {
                int m;
                if (ni < 12) m = 0; else if (ni < 16) m = 1; else if (ni < 23) m = 2;
                else if (ni < 32) m = 3; else if (ni < 46) m = 4; else if (ni < 64) m = 5;
                else if (ni < 91) m = 6; else if (ni < 128) m = 7; else m = 8;
                val = 8 + m;
                if (val > 15) val = 15;
            }
            d += relb[(ret + val) * H + hd];
            if (tokens[key] == PADIDX) d += -1e30f;
            sc = d;
        }
        scores[c] = sc;
        smax = fmaxf(smax, sc);
    }
#pragma unroll
    for (int off = 32; off; off >>= 1) smax = fmaxf(smax, __shfl_down(smax, off));
    smax = __shfl(smax, 0);

    float lsum = 0.0f;
#pragma unroll
    for (int c = 0; c < 5; c++) {
        int ki = c * 64 + lane;
        float p = 0.0f;
        if (ki < nk) { p = __expf(scores[c] - smax); p_s[ki] = p; }
        lsum += p;
    }
#pragma unroll
    for (int off = 32; off; off >>= 1) lsum += __shfl_down(lsum, off);
    lsum = __shfl(lsum, 0);
    __syncthreads();

    float inv = 1.0f / lsum;
    const unsigned short* vb = (const unsigned short*)qkv + (size_t)klo * 2304 + 1536 + hd * 64 + lane;
    float o = 0.0f;
    for (int i = 0; i < nk; i++) o += p_s[i] * bf2f(vb[(size_t)i * 2304]);
    out[(size_t)s * D + hd * 64 + lane] = __float2bfloat16(o * inv);
}

// ---------------- residual + layernorm ----------------
__global__ __launch_bounds__(256) void ln_kernel(const float* __restrict__ x, const float* __restrict__ add,
                                                 const float* __restrict__ sc, const float* __restrict__ bi,
                                                 float* __restrict__ out, bf16* __restrict__ out_bf) {
    int row = blockIdx.x, t = threadIdx.x;
    float v[3];
    float lsum = 0.0f, lsq = 0.0f;
#pragma unroll
    for (int i = 0; i < 3; i++) {
        int c = t + i * 256;
        float val = x[(size_t)row * D + c] + add[(size_t)row * D + c];
        v[i] = val; lsum += val; lsq += val * val;
    }
#pragma unroll
    for (int off = 32; off; off >>= 1) { lsum += __shfl_down(lsum, off); lsq += __shfl_down(lsq, off); }
    __shared__ float s1[4], s2[4];
    if ((t & 63) == 0) { s1[t >> 6] = lsum; s2[t >> 6] = lsq; }
    __syncthreads();
    float tot = s1[0] + s1[1] + s1[2] + s1[3];
    float tot2 = s2[0] + s2[1] + s2[2] + s2[3];
    float mean = tot * (1.0f / 768.0f);
    float var = tot2 * (1.0f / 768.0f) - mean * mean;
    float rstd = rsqrtf(var + 1e-5f);
#pragma unroll
    for (int i = 0; i < 3; i++) {
        int c = t + i * 256;
        float y = (v[i] - mean) * rstd * sc[c] + bi[c];
        out[(size_t)row * D + c] = y;
        out_bf[(size_t)row * D + c] = __float2bfloat16(y);
    }
}

extern "C" void kernel_launch(void* const* d_in, const int* in_sizes, int n_in,
                              void* d_out, int out_size, void* d_ws, size_t ws_size,
                              hipStream_t stream) {
    const int* tokens = (const int*)d_in[0];
    const int* seg = (const int*)d_in[1];
    const float* emb = (const float*)d_in[2];
    const float* pemb = (const float*)d_in[3];
    const float* semb = (const float*)d_in[4];
    const float* relb = (const float*)d_in[5];
    const float* Wq = (const float*)d_in[6];  const float* bq = (const float*)d_in[7];
    const float* Wk = (const float*)d_in[8];  const float* bk = (const float*)d_in[9];
    const float* Wv = (const float*)d_in[10]; const float* bv = (const float*)d_in[11];
    const float* Wo = (const float*)d_in[12]; const float* bo = (const float*)d_in[13];
    const float* ln1s = (const float*)d_in[14]; const float* ln1b = (const float*)d_in[15];
    const float* W1 = (const float*)d_in[16]; const float* b1 = (const float*)d_in[17];
    const float* W2 = (const float*)d_in[18]; const float* b2 = (const float*)d_in[19];
    const float* ln2s = (const float*)d_in[20]; const float* ln2b = (const float*)d_in[21];

    char* base = (char*)d_ws;
    size_t off = 0;
    auto take = [&](size_t bytes) -> char* {
        char* p = base + off;
        off = (off + bytes + 255) & ~(size_t)255;
        return p;
    };
    int* positions = (int*)take((size_t)S * 4);
    float* h       = (float*)take((size_t)S * D * 4);
    bf16* h_bf     = (bf16*)take((size_t)S * D * 2);
    float* tmp     = (float*)take((size_t)S * D * 4);
    bf16* qkv      = (bf16*)take((size_t)S * 2304 * 2);
    bf16* attnO    = (bf16*)take((size_t)S * D * 2);
    bf16* ff1      = (bf16*)take((size_t)S * FF * 2);
    bf16* Wqkv_t   = (bf16*)take((size_t)NL * 2304 * 768 * 2);
    bf16* Wo_t     = (bf16*)take((size_t)NL * 768 * 768 * 2);
    bf16* W1_t     = (bf16*)take((size_t)NL * 3072 * 768 * 2);
    bf16* W2_t     = (bf16*)take((size_t)NL * 768 * 3072 * 2);
    (void)ws_size; (void)n_in; (void)in_sizes;

    positions_kernel<<<1, 256, 0, stream>>>(tokens, positions);
    embed_kernel<<<S, 256, 0, stream>>>(tokens, seg, positions, emb, pemb, semb, h, h_bf);

    // weight transposes (fp32 [K,N] -> bf16 [N,K]) for all 6 layers
    transpose_convert<<<dim3(12, 12, NL), 256, 0, stream>>>(Wq, Wqkv_t, 768, 768, 768L * 768, 2304L * 768);
    transpose_convert<<<dim3(12, 12, NL), 256, 0, stream>>>(Wk, Wqkv_t + 768L * 768, 768, 768, 768L * 768, 2304L * 768);
    transpose_convert<<<dim3(12, 12, NL), 256, 0, stream>>>(Wv, Wqkv_t + 1536L * 768, 768, 768, 768L * 768, 2304L * 768);
    transpose_convert<<<dim3(12, 12, NL), 256, 0, stream>>>(Wo, Wo_t, 768, 768, 768L * 768, 768L * 768);
    transpose_convert<<<dim3(12, 48, NL), 256, 0, stream>>>(W1, W1_t, 768, 3072, 768L * 3072, 3072L * 768);
    transpose_convert<<<dim3(48, 12, NL), 256, 0, stream>>>(W2, W2_t, 3072, 768, 3072L * 768, 768L * 3072);

    for (int l = 0; l < NL; l++) {
        gemm_kernel<0><<<dim3(16, 18), 256, 0, stream>>>(h_bf, Wqkv_t + (size_t)l * 2304 * 768,
                                                         bq + l * 768, bk + l * 768, bv + l * 768,
                                                         nullptr, qkv, S, 2304, 768);
        attn_kernel<<<dim3(S, H), 64, 0, stream>>>(qkv, tokens, relb, attnO);
        gemm_kernel<1><<<dim3(16, 6), 256, 0, stream>>>(attnO, Wo_t + (size_t)l * 768 * 768,
                                                        bo + l * 768, nullptr, nullptr,
                                                        tmp, nullptr, S, 768, 768);
        ln_kernel<<<S, 256, 0, stream>>>(h, tmp, ln1s + l * 768, ln1b + l * 768, h, h_bf);
        gemm_kernel<2><<<dim3(16, 24), 256, 0, stream>>>(h_bf, W1_t + (size_t)l * 3072 * 768,
                                                         b1 + l * 3072, nullptr, nullptr,
                                                         nullptr, ff1, S, 3072, 768);
        gemm_kernel<1><<<dim3(16, 6), 256, 0, stream>>>(ff1, W2_t + (size_t)l * 768 * 3072,
                                                        b2 + l * 768, nullptr, nullptr,
                                                        tmp, nullptr, S, 768, 3072);
        ln_kernel<<<S, 256, 0, stream>>>(h, tmp, ln2s + l * 768, ln2b + l * 768, h, h_bf);
    }
    hipMemcpyAsync(d_out, h, (size_t)out_size * 4, hipMemcpyDeviceToDevice, stream);
}

// Round 2
// 1322.759 us; speedup vs baseline: 1.6937x; 1.6937x over previous
//
#include <hip/hip_runtime.h>
#include <hip/hip_bf16.h>

// Problem constants
#define S 2048
#define D 768
#define H 12
#define HD 64
#define FF 3072
#define NL 6
#define WIN 128
#define PADIDX 1

typedef __hip_bfloat16 bf16;
typedef __attribute__((ext_vector_type(8))) __bf16 bf16x8;
typedef __attribute__((ext_vector_type(4))) float f32x4;
typedef __attribute__((ext_vector_type(8))) unsigned short u16x8;

__device__ __forceinline__ unsigned short f2bfu(float f) {
    bf16 b = __float2bfloat16(f);
    return *(unsigned short*)&b;
}

// async global->LDS, 16B per lane. LDS base must be wave-uniform.
__device__ __forceinline__ void g2l16(const bf16* g, bf16* l) {
    __builtin_amdgcn_global_load_lds((__attribute__((address_space(1))) void*)(g),
                                     (__attribute__((address_space(3))) void*)(l), 16, 0, 0);
}

// ---------------- positions (fairseq make_positions) ----------------
__global__ void positions_kernel(const int* __restrict__ tokens, int* __restrict__ positions) {
    __shared__ int sums[256];
    int t = threadIdx.x;
    int np[8]; int loc = 0;
    for (int i = 0; i < 8; i++) { np[i] = (tokens[t * 8 + i] != PADIDX) ? 1 : 0; loc += np[i]; }
    sums[t] = loc;
    __syncthreads();
    for (int off = 1; off < 256; off <<= 1) {
        int u = (t >= off) ? sums[t - off] : 0;
        __syncthreads();
        sums[t] += u;
        __syncthreads();
    }
    int run = (t > 0) ? sums[t - 1] : 0;
    for (int i = 0; i < 8; i++) {
        run += np[i];
        positions[t * 8 + i] = np[i] ? (PADIDX + run) : PADIDX;
    }
}

// ---------------- embedding ----------------
__global__ void embed_kernel(const int* __restrict__ tokens, const int* __restrict__ seg,
                             const int* __restrict__ positions,
                             const float* __restrict__ emb, const float* __restrict__ pemb,
                             const float* __restrict__ semb,
                             float* __restrict__ h, bf16* __restrict__ h_bf) {
    int s = blockIdx.x, t = threadIdx.x;
    int tok = tokens[s];
    int pos = positions[s];
    int sg = seg[s];
    bool pad = (tok == PADIDX);
    for (int i = 0; i < 3; i++) {
        int c = t + i * 256;
        float val = emb[(size_t)tok * D + c] + pemb[(size_t)pos * D + c] + semb[(size_t)sg * D + c];
        if (pad) val = 0.0f;
        h[(size_t)s * D + c] = val;
        h_bf[(size_t)s * D + c] = __float2bfloat16(val);
    }
}

// ---------------- fp32 [K,N] -> bf16 [N,K] transpose+convert ----------------
__global__ void transpose_convert(const float* __restrict__ src, bf16* __restrict__ dst,
                                  int K, int N, long srcLS, long dstLS) {
    src += (long)blockIdx.z * srcLS;
    dst += (long)blockIdx.z * dstLS;
    __shared__ float tile[64][65];
    int k0 = blockIdx.x * 64, n0 = blockIdx.y * 64;
    int t = threadIdx.x;
    for (int i = t; i < 4096; i += 256) {
        int r = i >> 6, c = i & 63;
        tile[r][c] = src[(long)(k0 + r) * N + n0 + c];
    }
    __syncthreads();
    for (int i = t; i < 4096; i += 256) {
        int r = i >> 6, c = i & 63;
        dst[(long)(n0 + r) * K + k0 + c] = __float2bfloat16(tile[c][r]);
    }
}

// ---------------- GEMM: C[M,N] = A[M,K] @ Bt[N,K]^T (+epilogue) ----------------
// MODE 0: qkv  -> (acc + bias{q,k,v}[col]) * (col<768 ? 0.125 : 1), bf16 out
// MODE 1: bias -> acc + bias0[col], fp32 out
// MODE 2: ff1  -> relu(acc + bias0[col]), bf16 out
template <int MODE>
__global__ __launch_bounds__(256) void gemm_kernel(
    const bf16* __restrict__ A, const bf16* __restrict__ Bt,
    const float* __restrict__ bias0, const float* __restrict__ bias1, const float* __restrict__ bias2,
    float* __restrict__ outF, bf16* __restrict__ outB, int M, int N, int K) {
    __shared__ __align__(16) bf16 As[128 * 32];
    __shared__ __align__(16) bf16 Bs[128 * 32];
    int t = threadIdx.x;
    int lane = t & 63, w = t >> 6;
    int m0 = blockIdx.x * 128, n0 = blockIdx.y * 128;
    int wm = (w & 1) * 64, wn = (w >> 1) * 64;
    int qd = lane >> 4, l16 = lane & 15;

    f32x4 acc[4][4] = {};

    int ll0 = t, ll1 = t + 256;
    const bf16* Ag0 = A + (size_t)(m0 + (ll0 >> 2)) * K + (ll0 & 3) * 8;
    const bf16* Ag1 = A + (size_t)(m0 + (ll1 >> 2)) * K + (ll1 & 3) * 8;
    const bf16* Bg0 = Bt + (size_t)(n0 + (ll0 >> 2)) * K + (ll0 & 3) * 8;
    const bf16* Bg1 = Bt + (size_t)(n0 + (ll1 >> 2)) * K + (ll1 & 3) * 8;
    bf16* Al0 = As + (size_t)(t & ~63) * 8;
    bf16* Al1 = As + (size_t)(256 + (t & ~63)) * 8;
    bf16* Bl0 = Bs + (size_t)(t & ~63) * 8;
    bf16* Bl1 = Bs + (size_t)(256 + (t & ~63)) * 8;

    int nkt = K >> 5;
    for (int kt = 0; kt < nkt; ++kt) {
        int ko = kt * 32;
        g2l16(Ag0 + ko, Al0);
        g2l16(Ag1 + ko, Al1);
        g2l16(Bg0 + ko, Bl0);
        g2l16(Bg1 + ko, Bl1);
        __syncthreads();
        bf16x8 aF[4], bF[4];
#pragma unroll
        for (int mi = 0; mi < 4; mi++) aF[mi] = *(const bf16x8*)&As[(wm + mi * 16 + l16) * 32 + qd * 8];
#pragma unroll
        for (int ni = 0; ni < 4; ni++) bF[ni] = *(const bf16x8*)&Bs[(wn + ni * 16 + l16) * 32 + qd * 8];
#pragma unroll
        for (int mi = 0; mi < 4; mi++)
#pragma unroll
            for (int ni = 0; ni < 4; ni++)
                acc[mi][ni] = __builtin_amdgcn_mfma_f32_16x16x32_bf16(aF[mi], bF[ni], acc[mi][ni], 0, 0, 0);
        __syncthreads();
    }

#pragma unroll
    for (int ni = 0; ni < 4; ni++) {
        int col = n0 + wn + ni * 16 + l16;
        float bb;
        if (MODE == 0) bb = (col < 768) ? bias0[col] : ((col < 1536) ? bias1[col - 768] : bias2[col - 1536]);
        else bb = bias0[col];
#pragma unroll
        for (int mi = 0; mi < 4; mi++) {
            int row = m0 + wm + mi * 16 + qd * 4;
#pragma unroll
            for (int r = 0; r < 4; r++) {
                float v = acc[mi][ni][r] + bb;
                if (MODE == 0) {
                    if (col < 768) v *= 0.125f;  // 1/sqrt(64)
                    outB[(size_t)(row + r) * N + col] = __float2bfloat16(v);
                } else if (MODE == 1) {
                    outF[(size_t)(row + r) * N + col] = v;
                } else {
                    v = fmaxf(v, 0.0f);
                    outB[(size_t)(row + r) * N + col] = __float2bfloat16(v);
                }
            }
        }
    }
}

// ---------------- MFMA windowed attention ----------------
// One block = one (head, 32-query tile). Keys: 288-wide window in LDS.
// qkv: [S, 2304] bf16 (q|k|v), q pre-scaled by 1/8; out: [S, 768] bf16.
#define KT 288
#define KSTR 72   // Ks row stride (16B-aligned, bank-conflict-free)
#define VSTR 296  // Vt / Ps row stride
__global__ __launch_bounds__(256, 2) void attn_kernel(const bf16* __restrict__ qkv,
                                                      const int* __restrict__ tokens,
                                                      const float* __restrict__ relb,
                                                      bf16* __restrict__ out) {
    const int q0 = blockIdx.x * 32;
    const int h = blockIdx.y;
    const int t = threadIdx.x;
    const int lane = t & 63, w = t >> 6;
    const int l16 = lane & 15, qd = lane >> 4;
    const int klo = max(0, q0 - WIN);

    __shared__ __align__(16) unsigned short KsPs[KT * KSTR];  // K [288][72]; later P [32][296]
    __shared__ __align__(16) unsigned short VtS[64 * VSTR];   // V^T [64][296]
    __shared__ float rbS[260];        // rel-bias + window mask, d=s-key clamped to [-129,129]
    __shared__ float wmaxS[4][32];
    __shared__ float wsumS[4][32];
    __shared__ char kmS[KT];          // pad-key / out-of-seq mask

    const unsigned short* qkvu = (const unsigned short*)qkv;

    // ---- stage K [288][64] -> KsPs[key][d], stride 72 ----
#pragma unroll
    for (int j = 0; j < 9; j++) {
        int i = j * 256 + t;            // 2304 tasks: (key, oct)
        int key = i >> 3, oct = i & 7;
        int ksrc = min(klo + key, S - 1);
        *(u16x8*)&KsPs[key * KSTR + oct * 8] =
            *(const u16x8*)(qkvu + (size_t)ksrc * 2304 + 768 + h * 64 + oct * 8);
    }
    // ---- stage V^T: VtS[d][key], stride 296 (transpose in flight) ----
#pragma unroll
    for (int j = 0; j < 9; j++) {
        int i = j * 256 + t;            // 2304 tasks: (oct, key) key-major for LDS banks
        int oct = i / KT;
        int key = i - oct * KT;
        int ksrc = min(klo + key, S - 1);
        u16x8 v = *(const u16x8*)(qkvu + (size_t)ksrc * 2304 + 1536 + h * 64 + oct * 8);
#pragma unroll
        for (int u = 0; u < 8; u++) VtS[(oct * 8 + u) * VSTR + key] = v[u];
    }
    // ---- rel-bias + window mask table ----
    for (int idx = t; idx < 260; idx += 256) {
        int dd = idx - 129;  // dd = s - key (= n in reference)
        float bv = -1e30f;
        if (dd >= -128 && dd <= 128) {
            int ni = dd, ret = 0;
            if (ni < 0) { ret = 16; ni = -ni; }
            int val;
            if (ni < 8) val = ni;
            else {
                int m;
                if (ni < 12) m = 0; else if (ni < 16) m = 1; else if (ni < 23) m = 2;
                else if (ni < 32) m = 3; else if (ni < 46) m = 4; else if (ni < 64) m = 5;
                else if (ni < 91) m = 6; else if (ni < 128) m = 7; else m = 8;
                val = 8 + m;
                if (val > 15) val = 15;
            }
            bv = relb[(ret + val) * H + h];
        }
        rbS[idx] = bv;
    }
    for (int idx = t; idx < KT; idx += 256) {
        int key = klo + idx;
        kmS[idx] = (key < S && tokens[key] != PADIDX) ? 0 : 1;
    }
    __syncthreads();

    // ---- Q fragments straight from global (q pre-scaled in QKV epilogue) ----
    bf16x8 Qf[2][2];
#pragma unroll
    for (int qt = 0; qt < 2; qt++)
#pragma unroll
        for (int ko = 0; ko < 2; ko++)
            Qf[qt][ko] = *(const bf16x8*)(qkvu + (size_t)(q0 + qt * 16 + l16) * 2304 + h * 64 + ko * 32 + qd * 8);

    // ---- QK^T: wave w owns key-tiles kt = w + 4j ----
    f32x4 acc[2][5] = {};
#pragma unroll
    for (int j = 0; j < 5; j++) {
        int kt = w + 4 * j;
        if (kt < 18) {
            bf16x8 b0 = *(const bf16x8*)&KsPs[(kt * 16 + l16) * KSTR + qd * 8];
            bf16x8 b1 = *(const bf16x8*)&KsPs[(kt * 16 + l16) * KSTR + 32 + qd * 8];
#pragma unroll
            for (int qt = 0; qt < 2; qt++) {
                acc[qt][j] = __builtin_amdgcn_mfma_f32_16x16x32_bf16(Qf[qt][0], b0, acc[qt][j], 0, 0, 0);
                acc[qt][j] = __builtin_amdgcn_mfma_f32_16x16x32_bf16(Qf[qt][1], b1, acc[qt][j], 0, 0, 0);
            }
        }
    }

    // ---- bias + mask + row max (C-layout: row=qd*4+r, col=l16) ----
    float rmax[2][4];
#pragma unroll
    for (int qt = 0; qt < 2; qt++)
#pragma unroll
        for (int r = 0; r < 4; r++) rmax[qt][r] = -3e38f;
    const int qmk = q0 - klo;
#pragma unroll
    for (int j = 0; j < 5; j++) {
        int kt = w + 4 * j;
        if (kt < 18) {
            int kidx = kt * 16 + l16;
            float km = kmS[kidx] ? -1e30f : 0.0f;
#pragma unroll
            for (int qt = 0; qt < 2; qt++)
#pragma unroll
                for (int r = 0; r < 4; r++) {
                    int dd = qmk + qt * 16 + qd * 4 + r - kidx;
                    dd = min(129, max(-129, dd));
                    float sc = acc[qt][j][r] + rbS[dd + 129] + km;
                    acc[qt][j][r] = sc;
                    rmax[qt][r] = fmaxf(rmax[qt][r], sc);
                }
        }
    }
#pragma unroll
    for (int m = 1; m < 16; m <<= 1)
#pragma unroll
        for (int qt = 0; qt < 2; qt++)
#pragma unroll
            for (int r = 0; r < 4; r++)
                rmax[qt][r] = fmaxf(rmax[qt][r], __shfl_xor(rmax[qt][r], m));
    if (l16 == 0) {
#pragma unroll
        for (int qt = 0; qt < 2; qt++)
#pragma unroll
            for (int r = 0; r < 4; r++) wmaxS[w][qt * 16 + qd * 4 + r] = rmax[qt][r];
    }
    __syncthreads();  // also orders: Ks reads done before Ps overwrites

    float gmax[2][4];
#pragma unroll
    for (int qt = 0; qt < 2; qt++)
#pragma unroll
        for (int r = 0; r < 4; r++) {
            int row = qt * 16 + qd * 4 + r;
            gmax[qt][r] = fmaxf(fmaxf(wmaxS[0][row], wmaxS[1][row]), fmaxf(wmaxS[2][row], wmaxS[3][row]));
        }

    // ---- exp, write P (bf16, A-layout rows) into Ks buffer, partial sums ----
    float lsum[2][4] = {};
#pragma unroll
    for (int j = 0; j < 5; j++) {
        int kt = w + 4 * j;
        if (kt < 18) {
#pragma unroll
            for (int qt = 0; qt < 2; qt++)
#pragma unroll
                for (int r = 0; r < 4; r++) {
                    float p = __expf(acc[qt][j][r] - gmax[qt][r]);
                    lsum[qt][r] += p;
                    KsPs[(qt * 16 + qd * 4 + r) * VSTR + kt * 16 + l16] = f2bfu(p);
                }
        }
    }
#pragma unroll
    for (int m = 1; m < 16; m <<= 1)
#pragma unroll
        for (int qt = 0; qt < 2; qt++)
#pragma unroll
            for (int r = 0; r < 4; r++) lsum[qt][r] += __shfl_xor(lsum[qt][r], m);
    if (l16 == 0) {
#pragma unroll
        for (int qt = 0; qt < 2; qt++)
#pragma unroll
            for (int r = 0; r < 4; r++) wsumS[w][qt * 16 + qd * 4 + r] = lsum[qt][r];
    }
    __syncthreads();  // P + sums visible

    // ---- PV: wave w -> qt = w&1, d-tiles dt0, dt0+1 ----
    {
        int qt = w & 1, dt0 = (w >> 1) * 2;
        f32x4 o0 = {}, o1 = {};
#pragma unroll
        for (int kk = 0; kk < 9; kk++) {
            bf16x8 aP = *(const bf16x8*)&KsPs[(qt * 16 + l16) * VSTR + kk * 32 + qd * 8];
            bf16x8 v0 = *(const bf16x8*)&VtS[(dt0 * 16 + l16) * VSTR + kk * 32 + qd * 8];
            bf16x8 v1 = *(const bf16x8*)&VtS[((dt0 + 1) * 16 + l16) * VSTR + kk * 32 + qd * 8];
            o0 = __builtin_amdgcn_mfma_f32_16x16x32_bf16(aP, v0, o0, 0, 0, 0);
            o1 = __builtin_amdgcn_mfma_f32_16x16x32_bf16(aP, v1, o1, 0, 0, 0);
        }
#pragma unroll
        for (int r = 0; r < 4; r++) {
            int row = qt * 16 + qd * 4 + r;
            float ts = wsumS[0][row] + wsumS[1][row] + wsumS[2][row] + wsumS[3][row];
            float inv = 1.0f / ts;
            size_t obase = (size_t)(q0 + row) * D + h * 64;
            out[obase + dt0 * 16 + l16] = __float2bfloat16(o0[r] * inv);
            out[obase + (dt0 + 1) * 16 + l16] = __float2bfloat16(o1[r] * inv);
        }
    }
}

// ---------------- residual + layernorm ----------------
__global__ __launch_bounds__(256) void ln_kernel(const float* __restrict__ x, const float* __restrict__ add,
                                                 const float* __restrict__ sc, const float* __restrict__ bi,
                                                 float* __restrict__ out, bf16* __restrict__ out_bf) {
    int row = blockIdx.x, t = threadIdx.x;
    float v[3];
    float lsum = 0.0f, lsq = 0.0f;
#pragma unroll
    for (int i = 0; i < 3; i++) {
        int c = t + i * 256;
        float val = x[(size_t)row * D + c] + add[(size_t)row * D + c];
        v[i] = val; lsum += val; lsq += val * val;
    }
#pragma unroll
    for (int off = 32; off; off >>= 1) { lsum += __shfl_down(lsum, off); lsq += __shfl_down(lsq, off); }
    __shared__ float s1[4], s2[4];
    if ((t & 63) == 0) { s1[t >> 6] = lsum; s2[t >> 6] = lsq; }
    __syncthreads();
    float tot = s1[0] + s1[1] + s1[2] + s1[3];
    float tot2 = s2[0] + s2[1] + s2[2] + s2[3];
    float mean = tot * (1.0f / 768.0f);
    float var = tot2 * (1.0f / 768.0f) - mean * mean;
    float rstd = rsqrtf(var + 1e-5f);
#pragma unroll
    for (int i = 0; i < 3; i++) {
        int c = t + i * 256;
        float y = (v[i] - mean) * rstd * sc[c] + bi[c];
        out[(size_t)row * D + c] = y;
        out_bf[(size_t)row * D + c] = __float2bfloat16(y);
    }
}

extern "C" void kernel_launch(void* const* d_in, const int* in_sizes, int n_in,
                              void* d_out, int out_size, void* d_ws, size_t ws_size,
                              hipStream_t stream) {
    const int* tokens = (const int*)d_in[0];
    const int* seg = (const int*)d_in[1];
    const float* emb = (const float*)d_in[2];
    const float* pemb = (const float*)d_in[3];
    const float* semb = (const float*)d_in[4];
    const float* relb = (const float*)d_in[5];
    const float* Wq = (const float*)d_in[6];  const float* bq = (const float*)d_in[7];
    const float* Wk = (const float*)d_in[8];  const float* bk = (const float*)d_in[9];
    const float* Wv = (const float*)d_in[10]; const float* bv = (const float*)d_in[11];
    const float* Wo = (const float*)d_in[12]; const float* bo = (const float*)d_in[13];
    const float* ln1s = (const float*)d_in[14]; const float* ln1b = (const float*)d_in[15];
    const float* W1 = (const float*)d_in[16]; const float* b1 = (const float*)d_in[17];
    const float* W2 = (const float*)d_in[18]; const float* b2 = (const float*)d_in[19];
    const float* ln2s = (const float*)d_in[20]; const float* ln2b = (const float*)d_in[21];

    char* base = (char*)d_ws;
    size_t off = 0;
    auto take = [&](size_t bytes) -> char* {
        char* p = base + off;
        off = (off + bytes + 255) & ~(size_t)255;
        return p;
    };
    int* positions = (int*)take((size_t)S * 4);
    float* h       = (float*)take((size_t)S * D * 4);
    bf16* h_bf     = (bf16*)take((size_t)S * D * 2);
    float* tmp     = (float*)take((size_t)S * D * 4);
    bf16* qkv      = (bf16*)take((size_t)S * 2304 * 2);
    bf16* attnO    = (bf16*)take((size_t)S * D * 2);
    bf16* ff1      = (bf16*)take((size_t)S * FF * 2);
    bf16* Wqkv_t   = (bf16*)take((size_t)NL * 2304 * 768 * 2);
    bf16* Wo_t     = (bf16*)take((size_t)NL * 768 * 768 * 2);
    bf16* W1_t     = (bf16*)take((size_t)NL * 3072 * 768 * 2);
    bf16* W2_t     = (bf16*)take((size_t)NL * 768 * 3072 * 2);
    (void)ws_size; (void)n_in; (void)in_sizes;

    positions_kernel<<<1, 256, 0, stream>>>(tokens, positions);
    embed_kernel<<<S, 256, 0, stream>>>(tokens, seg, positions, emb, pemb, semb, h, h_bf);

    // weight transposes (fp32 [K,N] -> bf16 [N,K]) for all 6 layers
    transpose_convert<<<dim3(12, 12, NL), 256, 0, stream>>>(Wq, Wqkv_t, 768, 768, 768L * 768, 2304L * 768);
    transpose_convert<<<dim3(12, 12, NL), 256, 0, stream>>>(Wk, Wqkv_t + 768L * 768, 768, 768, 768L * 768, 2304L * 768);
    transpose_convert<<<dim3(12, 12, NL), 256, 0, stream>>>(Wv, Wqkv_t + 1536L * 768, 768, 768, 768L * 768, 2304L * 768);
    transpose_convert<<<dim3(12, 12, NL), 256, 0, stream>>>(Wo, Wo_t, 768, 768, 768L * 768, 768L * 768);
    transpose_convert<<<dim3(12, 48, NL), 256, 0, stream>>>(W1, W1_t, 768, 3072, 768L * 3072, 3072L * 768);
    transpose_convert<<<dim3(48, 12, NL), 256, 0, stream>>>(W2, W2_t, 3072, 768, 3072L * 768, 768L * 3072);

    for (int l = 0; l < NL; l++) {
        gemm_kernel<0><<<dim3(16, 18), 256, 0, stream>>>(h_bf, Wqkv_t + (size_t)l * 2304 * 768,
                                                         bq + l * 768, bk + l * 768, bv + l * 768,
                                                         nullptr, qkv, S, 2304, 768);
        attn_kernel<<<dim3(S / 32, H), 256, 0, stream>>>(qkv, tokens, relb, attnO);
        gemm_kernel<1><<<dim3(16, 6), 256, 0, stream>>>(attnO, Wo_t + (size_t)l * 768 * 768,
                                                        bo + l * 768, nullptr, nullptr,
                                                        tmp, nullptr, S, 768, 768);
        ln_kernel<<<S, 256, 0, stream>>>(h, tmp, ln1s + l * 768, ln1b + l * 768, h, h_bf);
        gemm_kernel<2><<<dim3(16, 24), 256, 0, stream>>>(h_bf, W1_t + (size_t)l * 3072 * 768,
                                                         b1 + l * 3072, nullptr, nullptr,
                                                         nullptr, ff1, S, 3072, 768);
        gemm_kernel<1><<<dim3(16, 6), 256, 0, stream>>>(ff1, W2_t + (size_t)l * 768 * 3072,
                                                        b2 + l * 768, nullptr, nullptr,
                                                        tmp, nullptr, S, 768, 3072);
        ln_kernel<<<S, 256, 0, stream>>>(h, tmp, ln2s + l * 768, ln2b + l * 768, h, h_bf);
    }
    hipMemcpyAsync(d_out, h, (size_t)out_size * 4, hipMemcpyDeviceToDevice, stream);
}

// Round 3
// 987.175 us; speedup vs baseline: 2.2695x; 1.3399x over previous
//
#include <hip/hip_runtime.h>
#include <hip/hip_bf16.h>

// Problem constants
#define S 2048
#define D 768
#define H 12
#define HD 64
#define FF 3072
#define NL 6
#define WIN 128
#define PADIDX 1

typedef __hip_bfloat16 bf16;
typedef __attribute__((ext_vector_type(8))) __bf16 bf16x8;
typedef __attribute__((ext_vector_type(4))) float f32x4;
typedef __attribute__((ext_vector_type(8))) unsigned short u16x8;

__device__ __forceinline__ unsigned short f2bfu(float f) {
    bf16 b = __float2bfloat16(f);
    return *(unsigned short*)&b;
}

// async global->LDS, 16B per lane. LDS base must be wave-uniform.
__device__ __forceinline__ void g2l16(const bf16* g, bf16* l) {
    __builtin_amdgcn_global_load_lds((__attribute__((address_space(1))) void*)(g),
                                     (__attribute__((address_space(3))) void*)(l), 16, 0, 0);
}

// ---------------- positions (fairseq make_positions) ----------------
__global__ void positions_kernel(const int* __restrict__ tokens, int* __restrict__ positions) {
    __shared__ int sums[256];
    int t = threadIdx.x;
    int np[8]; int loc = 0;
    for (int i = 0; i < 8; i++) { np[i] = (tokens[t * 8 + i] != PADIDX) ? 1 : 0; loc += np[i]; }
    sums[t] = loc;
    __syncthreads();
    for (int off = 1; off < 256; off <<= 1) {
        int u = (t >= off) ? sums[t - off] : 0;
        __syncthreads();
        sums[t] += u;
        __syncthreads();
    }
    int run = (t > 0) ? sums[t - 1] : 0;
    for (int i = 0; i < 8; i++) {
        run += np[i];
        positions[t * 8 + i] = np[i] ? (PADIDX + run) : PADIDX;
    }
}

// ---------------- embedding ----------------
__global__ void embed_kernel(const int* __restrict__ tokens, const int* __restrict__ seg,
                             const int* __restrict__ positions,
                             const float* __restrict__ emb, const float* __restrict__ pemb,
                             const float* __restrict__ semb,
                             float* __restrict__ h, bf16* __restrict__ h_bf) {
    int s = blockIdx.x, t = threadIdx.x;
    int tok = tokens[s];
    int pos = positions[s];
    int sg = seg[s];
    bool pad = (tok == PADIDX);
    for (int i = 0; i < 3; i++) {
        int c = t + i * 256;
        float val = emb[(size_t)tok * D + c] + pemb[(size_t)pos * D + c] + semb[(size_t)sg * D + c];
        if (pad) val = 0.0f;
        h[(size_t)s * D + c] = val;
        h_bf[(size_t)s * D + c] = __float2bfloat16(val);
    }
}

// ---------------- fp32 [K,N] -> bf16 [N,K] transpose+convert ----------------
__global__ void transpose_convert(const float* __restrict__ src, bf16* __restrict__ dst,
                                  int K, int N, long srcLS, long dstLS) {
    src += (long)blockIdx.z * srcLS;
    dst += (long)blockIdx.z * dstLS;
    __shared__ float tile[64][65];
    int k0 = blockIdx.x * 64, n0 = blockIdx.y * 64;
    int t = threadIdx.x;
    for (int i = t; i < 4096; i += 256) {
        int r = i >> 6, c = i & 63;
        tile[r][c] = src[(long)(k0 + r) * N + n0 + c];
    }
    __syncthreads();
    for (int i = t; i < 4096; i += 256) {
        int r = i >> 6, c = i & 63;
        dst[(long)(n0 + r) * K + k0 + c] = __float2bfloat16(tile[c][r]);
    }
}

// ---------------- GEMM 64x128 tile: C[M,N] = A[M,K] @ Bt[N,K]^T (+epilogue) ----------------
// MODE 0: qkv  -> (acc + bias{q,k,v}[col]) * (col<768 ? 0.125 : 1), bf16 out
// MODE 1: partial fp32 out (outF + z*M*N); bias0 added only on split z==0
// MODE 2: ff1  -> relu(acc + bias0[col]), bf16 out
template <int MODE>
__global__ __launch_bounds__(256, 4) void gemm64(
    const bf16* __restrict__ A, const bf16* __restrict__ Bt,
    const float* __restrict__ bias0, const float* __restrict__ bias1, const float* __restrict__ bias2,
    float* __restrict__ outF, bf16* __restrict__ outB, int M, int N, int K, int klen) {
    __shared__ __align__(16) bf16 As[64 * 32];
    __shared__ __align__(16) bf16 Bs[128 * 32];
    int t = threadIdx.x;
    int lane = t & 63, w = t >> 6;
    int m0 = blockIdx.x * 64, n0 = blockIdx.y * 128;
    int kbase = blockIdx.z * klen;
    int wm = (w & 1) * 32, wn = (w >> 1) * 64;
    int qd = lane >> 4, l16 = lane & 15;

    f32x4 acc[2][4] = {};

    int i1 = t + 256;
    const bf16* Ag  = A  + (size_t)(m0 + (t >> 2)) * K + kbase + (t & 3) * 8;
    const bf16* Bg0 = Bt + (size_t)(n0 + (t >> 2)) * K + kbase + (t & 3) * 8;
    const bf16* Bg1 = Bt + (size_t)(n0 + (i1 >> 2)) * K + kbase + (i1 & 3) * 8;
    bf16* Al  = As + (size_t)(t & ~63) * 8;
    bf16* Bl0 = Bs + (size_t)(t & ~63) * 8;
    bf16* Bl1 = Bs + (size_t)(256 + (t & ~63)) * 8;

    int nkt = klen >> 5;
    for (int kt = 0; kt < nkt; ++kt) {
        int ko = kt * 32;
        g2l16(Ag + ko, Al);
        g2l16(Bg0 + ko, Bl0);
        g2l16(Bg1 + ko, Bl1);
        __syncthreads();
        bf16x8 aF[2], bF[4];
#pragma unroll
        for (int mi = 0; mi < 2; mi++) aF[mi] = *(const bf16x8*)&As[(wm + mi * 16 + l16) * 32 + qd * 8];
#pragma unroll
        for (int ni = 0; ni < 4; ni++) bF[ni] = *(const bf16x8*)&Bs[(wn + ni * 16 + l16) * 32 + qd * 8];
#pragma unroll
        for (int mi = 0; mi < 2; mi++)
#pragma unroll
            for (int ni = 0; ni < 4; ni++)
                acc[mi][ni] = __builtin_amdgcn_mfma_f32_16x16x32_bf16(aF[mi], bF[ni], acc[mi][ni], 0, 0, 0);
        __syncthreads();
    }

#pragma unroll
    for (int ni = 0; ni < 4; ni++) {
        int col = n0 + wn + ni * 16 + l16;
        float bb;
        if (MODE == 0) bb = (col < 768) ? bias0[col] : ((col < 1536) ? bias1[col - 768] : bias2[col - 1536]);
        else if (MODE == 1) bb = (blockIdx.z == 0) ? bias0[col] : 0.0f;
        else bb = bias0[col];
#pragma unroll
        for (int mi = 0; mi < 2; mi++) {
            int row = m0 + wm + mi * 16 + qd * 4;
#pragma unroll
            for (int r = 0; r < 4; r++) {
                float v = acc[mi][ni][r] + bb;
                if (MODE == 0) {
                    if (col < 768) v *= 0.125f;  // 1/sqrt(64)
                    outB[(size_t)(row + r) * N + col] = __float2bfloat16(v);
                } else if (MODE == 1) {
                    outF[(size_t)blockIdx.z * M * N + (size_t)(row + r) * N + col] = v;
                } else {
                    v = fmaxf(v, 0.0f);
                    outB[(size_t)(row + r) * N + col] = __float2bfloat16(v);
                }
            }
        }
    }
}

// ---------------- MFMA windowed attention ----------------
// One block = one (head, 32-query tile). Keys: 288-wide window in LDS.
// qkv: [S, 2304] bf16 (q|k|v), q pre-scaled by 1/8; out: [S, 768] bf16.
#define KT 288
#define KSTR 72   // Ks row stride (16B-aligned)
#define VSTR 296  // Vt / Ps row stride
__global__ __launch_bounds__(256, 2) void attn_kernel(const bf16* __restrict__ qkv,
                                                      const int* __restrict__ tokens,
                                                      const float* __restrict__ relb,
                                                      bf16* __restrict__ out) {
    const int q0 = blockIdx.x * 32;
    const int h = blockIdx.y;
    const int t = threadIdx.x;
    const int lane = t & 63, w = t >> 6;
    const int l16 = lane & 15, qd = lane >> 4;
    const int klo = max(0, q0 - WIN);

    __shared__ __align__(16) unsigned short KsPs[KT * KSTR];  // K [288][72]; later P [32][296]
    __shared__ __align__(16) unsigned short VtS[64 * VSTR];   // V^T [64][296]
    __shared__ float rbS[260];
    __shared__ float wmaxS[4][32];
    __shared__ float wsumS[4][32];
    __shared__ char kmS[KT];

    const unsigned short* qkvu = (const unsigned short*)qkv;

#pragma unroll
    for (int j = 0; j < 9; j++) {
        int i = j * 256 + t;
        int key = i >> 3, oct = i & 7;
        int ksrc = min(klo + key, S - 1);
        *(u16x8*)&KsPs[key * KSTR + oct * 8] =
            *(const u16x8*)(qkvu + (size_t)ksrc * 2304 + 768 + h * 64 + oct * 8);
    }
#pragma unroll
    for (int j = 0; j < 9; j++) {
        int i = j * 256 + t;
        int oct = i / KT;
        int key = i - oct * KT;
        int ksrc = min(klo + key, S - 1);
        u16x8 v = *(const u16x8*)(qkvu + (size_t)ksrc * 2304 + 1536 + h * 64 + oct * 8);
#pragma unroll
        for (int u = 0; u < 8; u++) VtS[(oct * 8 + u) * VSTR + key] = v[u];
    }
    for (int idx = t; idx < 260; idx += 256) {
        int dd = idx - 129;
        float bv = -1e30f;
        if (dd >= -128 && dd <= 128) {
            int ni = dd, ret = 0;
            if (ni < 0) { ret = 16; ni = -ni; }
            int val;
            if (ni < 8) val = ni;
            else {
                int m;
                if (ni < 12) m = 0; else if (ni < 16) m = 1; else if (ni < 23) m = 2;
                else if (ni < 32) m = 3; else if (ni < 46) m = 4; else if (ni < 64) m = 5;
                else if (ni < 91) m = 6; else if (ni < 128) m = 7; else m = 8;
                val = 8 + m;
                if (val > 15) val = 15;
            }
            bv = relb[(ret + val) * H + h];
        }
        rbS[idx] = bv;
    }
    for (int idx = t; idx < KT; idx += 256) {
        int key = klo + idx;
        kmS[idx] = (key < S && tokens[key] != PADIDX) ? 0 : 1;
    }
    __syncthreads();

    bf16x8 Qf[2][2];
#pragma unroll
    for (int qt = 0; qt < 2; qt++)
#pragma unroll
        for (int ko = 0; ko < 2; ko++)
            Qf[qt][ko] = *(const bf16x8*)(qkvu + (size_t)(q0 + qt * 16 + l16) * 2304 + h * 64 + ko * 32 + qd * 8);

    f32x4 acc[2][5] = {};
#pragma unroll
    for (int j = 0; j < 5; j++) {
        int kt = w + 4 * j;
        if (kt < 18) {
            bf16x8 b0 = *(const bf16x8*)&KsPs[(kt * 16 + l16) * KSTR + qd * 8];
            bf16x8 b1 = *(const bf16x8*)&KsPs[(kt * 16 + l16) * KSTR + 32 + qd * 8];
#pragma unroll
            for (int qt = 0; qt < 2; qt++) {
                acc[qt][j] = __builtin_amdgcn_mfma_f32_16x16x32_bf16(Qf[qt][0], b0, acc[qt][j], 0, 0, 0);
                acc[qt][j] = __builtin_amdgcn_mfma_f32_16x16x32_bf16(Qf[qt][1], b1, acc[qt][j], 0, 0, 0);
            }
        }
    }

    float rmax[2][4];
#pragma unroll
    for (int qt = 0; qt < 2; qt++)
#pragma unroll
        for (int r = 0; r < 4; r++) rmax[qt][r] = -3e38f;
    const int qmk = q0 - klo;
#pragma unroll
    for (int j = 0; j < 5; j++) {
        int kt = w + 4 * j;
        if (kt < 18) {
            int kidx = kt * 16 + l16;
            float km = kmS[kidx] ? -1e30f : 0.0f;
#pragma unroll
            for (int qt = 0; qt < 2; qt++)
#pragma unroll
                for (int r = 0; r < 4; r++) {
                    int dd = qmk + qt * 16 + qd * 4 + r - kidx;
                    dd = min(129, max(-129, dd));
                    float sc = acc[qt][j][r] + rbS[dd + 129] + km;
                    acc[qt][j][r] = sc;
                    rmax[qt][r] = fmaxf(rmax[qt][r], sc);
                }
        }
    }
#pragma unroll
    for (int m = 1; m < 16; m <<= 1)
#pragma unroll
        for (int qt = 0; qt < 2; qt++)
#pragma unroll
            for (int r = 0; r < 4; r++)
                rmax[qt][r] = fmaxf(rmax[qt][r], __shfl_xor(rmax[qt][r], m));
    if (l16 == 0) {
#pragma unroll
        for (int qt = 0; qt < 2; qt++)
#pragma unroll
            for (int r = 0; r < 4; r++) wmaxS[w][qt * 16 + qd * 4 + r] = rmax[qt][r];
    }
    __syncthreads();

    float gmax[2][4];
#pragma unroll
    for (int qt = 0; qt < 2; qt++)
#pragma unroll
        for (int r = 0; r < 4; r++) {
            int row = qt * 16 + qd * 4 + r;
            gmax[qt][r] = fmaxf(fmaxf(wmaxS[0][row], wmaxS[1][row]), fmaxf(wmaxS[2][row], wmaxS[3][row]));
        }

    float lsum[2][4] = {};
#pragma unroll
    for (int j = 0; j < 5; j++) {
        int kt = w + 4 * j;
        if (kt < 18) {
#pragma unroll
            for (int qt = 0; qt < 2; qt++)
#pragma unroll
                for (int r = 0; r < 4; r++) {
                    float p = __expf(acc[qt][j][r] - gmax[qt][r]);
                    lsum[qt][r] += p;
                    KsPs[(qt * 16 + qd * 4 + r) * VSTR + kt * 16 + l16] = f2bfu(p);
                }
        }
    }
#pragma unroll
    for (int m = 1; m < 16; m <<= 1)
#pragma unroll
        for (int qt = 0; qt < 2; qt++)
#pragma unroll
            for (int r = 0; r < 4; r++) lsum[qt][r] += __shfl_xor(lsum[qt][r], m);
    if (l16 == 0) {
#pragma unroll
        for (int qt = 0; qt < 2; qt++)
#pragma unroll
            for (int r = 0; r < 4; r++) wsumS[w][qt * 16 + qd * 4 + r] = lsum[qt][r];
    }
    __syncthreads();

    {
        int qt = w & 1, dt0 = (w >> 1) * 2;
        f32x4 o0 = {}, o1 = {};
#pragma unroll
        for (int kk = 0; kk < 9; kk++) {
            bf16x8 aP = *(const bf16x8*)&KsPs[(qt * 16 + l16) * VSTR + kk * 32 + qd * 8];
            bf16x8 v0 = *(const bf16x8*)&VtS[(dt0 * 16 + l16) * VSTR + kk * 32 + qd * 8];
            bf16x8 v1 = *(const bf16x8*)&VtS[((dt0 + 1) * 16 + l16) * VSTR + kk * 32 + qd * 8];
            o0 = __builtin_amdgcn_mfma_f32_16x16x32_bf16(aP, v0, o0, 0, 0, 0);
            o1 = __builtin_amdgcn_mfma_f32_16x16x32_bf16(aP, v1, o1, 0, 0, 0);
        }
#pragma unroll
        for (int r = 0; r < 4; r++) {
            int row = qt * 16 + qd * 4 + r;
            float ts = wsumS[0][row] + wsumS[1][row] + wsumS[2][row] + wsumS[3][row];
            float inv = 1.0f / ts;
            size_t obase = (size_t)(q0 + row) * D + h * 64;
            out[obase + dt0 * 16 + l16] = __float2bfloat16(o0[r] * inv);
            out[obase + (dt0 + 1) * 16 + l16] = __float2bfloat16(o1[r] * inv);
        }
    }
}

// ---------------- residual + NP split-K partials + layernorm ----------------
template <int NP>
__global__ __launch_bounds__(256) void ln_kernel(const float* __restrict__ x, const float* __restrict__ parts,
                                                 const float* __restrict__ sc, const float* __restrict__ bi,
                                                 float* __restrict__ out, bf16* __restrict__ out_bf) {
    int row = blockIdx.x, t = threadIdx.x;
    float v[3];
    float lsum = 0.0f, lsq = 0.0f;
#pragma unroll
    for (int i = 0; i < 3; i++) {
        int c = t + i * 256;
        size_t idx = (size_t)row * D + c;
        float val = x[idx];
#pragma unroll
        for (int p = 0; p < NP; p++) val += parts[(size_t)p * S * D + idx];
        v[i] = val; lsum += val; lsq += val * val;
    }
#pragma unroll
    for (int off = 32; off; off >>= 1) { lsum += __shfl_down(lsum, off); lsq += __shfl_down(lsq, off); }
    __shared__ float s1[4], s2[4];
    if ((t & 63) == 0) { s1[t >> 6] = lsum; s2[t >> 6] = lsq; }
    __syncthreads();
    float tot = s1[0] + s1[1] + s1[2] + s1[3];
    float tot2 = s2[0] + s2[1] + s2[2] + s2[3];
    float mean = tot * (1.0f / 768.0f);
    float var = tot2 * (1.0f / 768.0f) - mean * mean;
    float rstd = rsqrtf(var + 1e-5f);
#pragma unroll
    for (int i = 0; i < 3; i++) {
        int c = t + i * 256;
        float y = (v[i] - mean) * rstd * sc[c] + bi[c];
        out[(size_t)row * D + c] = y;
        out_bf[(size_t)row * D + c] = __float2bfloat16(y);
    }
}

extern "C" void kernel_launch(void* const* d_in, const int* in_sizes, int n_in,
                              void* d_out, int out_size, void* d_ws, size_t ws_size,
                              hipStream_t stream) {
    const int* tokens = (const int*)d_in[0];
    const int* seg = (const int*)d_in[1];
    const float* emb = (const float*)d_in[2];
    const float* pemb = (const float*)d_in[3];
    const float* semb = (const float*)d_in[4];
    const float* relb = (const float*)d_in[5];
    const float* Wq = (const float*)d_in[6];  const float* bq = (const float*)d_in[7];
    const float* Wk = (const float*)d_in[8];  const float* bk = (const float*)d_in[9];
    const float* Wv = (const float*)d_in[10]; const float* bv = (const float*)d_in[11];
    const float* Wo = (const float*)d_in[12]; const float* bo = (const float*)d_in[13];
    const float* ln1s = (const float*)d_in[14]; const float* ln1b = (const float*)d_in[15];
    const float* W1 = (const float*)d_in[16]; const float* b1 = (const float*)d_in[17];
    const float* W2 = (const float*)d_in[18]; const float* b2 = (const float*)d_in[19];
    const float* ln2s = (const float*)d_in[20]; const float* ln2b = (const float*)d_in[21];

    char* base = (char*)d_ws;
    size_t off = 0;
    auto take = [&](size_t bytes) -> char* {
        char* p = base + off;
        off = (off + bytes + 255) & ~(size_t)255;
        return p;
    };
    int* positions = (int*)take((size_t)S * 4);
    float* h       = (float*)take((size_t)S * D * 4);
    bf16* h_bf     = (bf16*)take((size_t)S * D * 2);
    float* parts   = (float*)take((size_t)4 * S * D * 4);   // up to 4 split-K partials
    bf16* qkv      = (bf16*)take((size_t)S * 2304 * 2);
    bf16* attnO    = (bf16*)take((size_t)S * D * 2);
    bf16* ff1      = (bf16*)take((size_t)S * FF * 2);
    bf16* Wqkv_t   = (bf16*)take((size_t)NL * 2304 * 768 * 2);
    bf16* Wo_t     = (bf16*)take((size_t)NL * 768 * 768 * 2);
    bf16* W1_t     = (bf16*)take((size_t)NL * 3072 * 768 * 2);
    bf16* W2_t     = (bf16*)take((size_t)NL * 768 * 3072 * 2);
    (void)ws_size; (void)n_in; (void)in_sizes;

    positions_kernel<<<1, 256, 0, stream>>>(tokens, positions);
    embed_kernel<<<S, 256, 0, stream>>>(tokens, seg, positions, emb, pemb, semb, h, h_bf);

    transpose_convert<<<dim3(12, 12, NL), 256, 0, stream>>>(Wq, Wqkv_t, 768, 768, 768L * 768, 2304L * 768);
    transpose_convert<<<dim3(12, 12, NL), 256, 0, stream>>>(Wk, Wqkv_t + 768L * 768, 768, 768, 768L * 768, 2304L * 768);
    transpose_convert<<<dim3(12, 12, NL), 256, 0, stream>>>(Wv, Wqkv_t + 1536L * 768, 768, 768, 768L * 768, 2304L * 768);
    transpose_convert<<<dim3(12, 12, NL), 256, 0, stream>>>(Wo, Wo_t, 768, 768, 768L * 768, 768L * 768);
    transpose_convert<<<dim3(12, 48, NL), 256, 0, stream>>>(W1, W1_t, 768, 3072, 768L * 3072, 3072L * 768);
    transpose_convert<<<dim3(48, 12, NL), 256, 0, stream>>>(W2, W2_t, 3072, 768, 3072L * 768, 768L * 3072);

    for (int l = 0; l < NL; l++) {
        // QKV: M64 tiles -> 32x18 = 576 blocks
        gemm64<0><<<dim3(32, 18, 1), 256, 0, stream>>>(h_bf, Wqkv_t + (size_t)l * 2304 * 768,
                                                       bq + l * 768, bk + l * 768, bv + l * 768,
                                                       nullptr, qkv, S, 2304, 768, 768);
        attn_kernel<<<dim3(S / 32, H), 256, 0, stream>>>(qkv, tokens, relb, attnO);
        // O-proj: split-K=2 -> 32x6x2 = 384 blocks, partials summed in LN
        gemm64<1><<<dim3(32, 6, 2), 256, 0, stream>>>(attnO, Wo_t + (size_t)l * 768 * 768,
                                                      bo + l * 768, nullptr, nullptr,
                                                      parts, nullptr, S, 768, 768, 384);
        ln_kernel<2><<<S, 256, 0, stream>>>(h, parts, ln1s + l * 768, ln1b + l * 768, h, h_bf);
        // FF1: M64 tiles -> 32x24 = 768 blocks
        gemm64<2><<<dim3(32, 24, 1), 256, 0, stream>>>(h_bf, W1_t + (size_t)l * 3072 * 768,
                                                       b1 + l * 3072, nullptr, nullptr,
                                                       nullptr, ff1, S, 3072, 768, 768);
        // FF2: split-K=4 -> 32x6x4 = 768 blocks
        gemm64<1><<<dim3(32, 6, 4), 256, 0, stream>>>(ff1, W2_t + (size_t)l * 768 * 3072,
                                                      b2 + l * 768, nullptr, nullptr,
                                                      parts, nullptr, S, 768, 3072, 768);
        ln_kernel<4><<<S, 256, 0, stream>>>(h, parts, ln2s + l * 768, ln2b + l * 768, h, h_bf);
    }
    hipMemcpyAsync(d_out, h, (size_t)out_size * 4, hipMemcpyDeviceToDevice, stream);
}

// Round 4
// 964.979 us; speedup vs baseline: 2.3217x; 1.0230x over previous
//
#include <hip/hip_runtime.h>
#include <hip/hip_bf16.h>

// Problem constants
#define S 2048
#define D 768
#define H 12
#define HD 64
#define FF 3072
#define NL 6
#define WIN 128
#define PADIDX 1

typedef __hip_bfloat16 bf16;
typedef __attribute__((ext_vector_type(8))) __bf16 bf16x8;
typedef __attribute__((ext_vector_type(4))) float f32x4;
typedef __attribute__((ext_vector_type(8))) unsigned short u16x8;

__device__ __forceinline__ unsigned short f2bfu(float f) {
    bf16 b = __float2bfloat16(f);
    return *(unsigned short*)&b;
}

// async global->LDS, 16B per lane. LDS base must be wave-uniform.
__device__ __forceinline__ void g2l16(const bf16* g, bf16* l) {
    __builtin_amdgcn_global_load_lds((__attribute__((address_space(1))) void*)(g),
                                     (__attribute__((address_space(3))) void*)(l), 16, 0, 0);
}

// ---------------- positions (fairseq make_positions) ----------------
__global__ void positions_kernel(const int* __restrict__ tokens, int* __restrict__ positions) {
    __shared__ int sums[256];
    int t = threadIdx.x;
    int np[8]; int loc = 0;
    for (int i = 0; i < 8; i++) { np[i] = (tokens[t * 8 + i] != PADIDX) ? 1 : 0; loc += np[i]; }
    sums[t] = loc;
    __syncthreads();
    for (int off = 1; off < 256; off <<= 1) {
        int u = (t >= off) ? sums[t - off] : 0;
        __syncthreads();
        sums[t] += u;
        __syncthreads();
    }
    int run = (t > 0) ? sums[t - 1] : 0;
    for (int i = 0; i < 8; i++) {
        run += np[i];
        positions[t * 8 + i] = np[i] ? (PADIDX + run) : PADIDX;
    }
}

// ---------------- embedding ----------------
__global__ void embed_kernel(const int* __restrict__ tokens, const int* __restrict__ seg,
                             const int* __restrict__ positions,
                             const float* __restrict__ emb, const float* __restrict__ pemb,
                             const float* __restrict__ semb,
                             float* __restrict__ h, bf16* __restrict__ h_bf) {
    int s = blockIdx.x, t = threadIdx.x;
    int tok = tokens[s];
    int pos = positions[s];
    int sg = seg[s];
    bool pad = (tok == PADIDX);
    for (int i = 0; i < 3; i++) {
        int c = t + i * 256;
        float val = emb[(size_t)tok * D + c] + pemb[(size_t)pos * D + c] + semb[(size_t)sg * D + c];
        if (pad) val = 0.0f;
        h[(size_t)s * D + c] = val;
        h_bf[(size_t)s * D + c] = __float2bfloat16(val);
    }
}

// ---------------- fp32 [K,N] -> bf16 [N,K] transpose+convert ----------------
__global__ void transpose_convert(const float* __restrict__ src, bf16* __restrict__ dst,
                                  int K, int N, long srcLS, long dstLS) {
    src += (long)blockIdx.z * srcLS;
    dst += (long)blockIdx.z * dstLS;
    __shared__ float tile[64][65];
    int k0 = blockIdx.x * 64, n0 = blockIdx.y * 64;
    int t = threadIdx.x;
    for (int i = t; i < 4096; i += 256) {
        int r = i >> 6, c = i & 63;
        tile[r][c] = src[(long)(k0 + r) * N + n0 + c];
    }
    __syncthreads();
    for (int i = t; i < 4096; i += 256) {
        int r = i >> 6, c = i & 63;
        dst[(long)(n0 + r) * K + k0 + c] = __float2bfloat16(tile[c][r]);
    }
}

// ---------------- GEMM 64x128 tile: C[M,N] = A[M,K] @ Bt[N,K]^T (+epilogue) ----------------
// LDS k-oct XOR swizzle: element (row, oct) lives at slot row*4 + (oct ^ ((row>>1)&3)),
// making the MFMA-fragment ds_read_b128 2-way (free) instead of 8-way bank-conflicted,
// while the global side stays a within-64B permutation (fully coalesced).
// MODE 0: qkv  -> (acc + bias{q,k,v}[col]) * (col<768 ? 0.125 : 1), bf16 out
// MODE 1: partial fp32 out (outF + z*M*N); bias0 added only on split z==0
// MODE 2: ff1  -> relu(acc + bias0[col]), bf16 out
template <int MODE>
__global__ __launch_bounds__(256, 4) void gemm64(
    const bf16* __restrict__ A, const bf16* __restrict__ Bt,
    const float* __restrict__ bias0, const float* __restrict__ bias1, const float* __restrict__ bias2,
    float* __restrict__ outF, bf16* __restrict__ outB, int M, int N, int K, int klen) {
    __shared__ __align__(16) bf16 As[64 * 32];
    __shared__ __align__(16) bf16 Bs[128 * 32];
    int t = threadIdx.x;
    int lane = t & 63, w = t >> 6;
    int m0 = blockIdx.x * 64, n0 = blockIdx.y * 128;
    int kbase = blockIdx.z * klen;
    int wm = (w & 1) * 32, wn = (w >> 1) * 64;
    int qd = lane >> 4, l16 = lane & 15;

    f32x4 acc[2][4] = {};

    int i1 = t + 256;
    // swizzled global k-oct per staging lane
    int oA  = ((t & 3) ^ ((t >> 3) & 3)) * 8;
    int oB1 = ((i1 & 3) ^ ((i1 >> 3) & 3)) * 8;
    const bf16* Ag  = A  + (size_t)(m0 + (t >> 2)) * K + kbase + oA;
    const bf16* Bg0 = Bt + (size_t)(n0 + (t >> 2)) * K + kbase + oA;
    const bf16* Bg1 = Bt + (size_t)(n0 + (i1 >> 2)) * K + kbase + oB1;
    bf16* Al  = As + (size_t)(t & ~63) * 8;
    bf16* Bl0 = Bs + (size_t)(t & ~63) * 8;
    bf16* Bl1 = Bs + (size_t)(256 + (t & ~63)) * 8;

    // swizzled LDS fragment offset (uniform across mi/ni since tile bases are mult of 16)
    int soct = (qd ^ ((l16 >> 1) & 3)) * 8;

    int nkt = klen >> 5;
    for (int kt = 0; kt < nkt; ++kt) {
        int ko = kt * 32;
        g2l16(Ag + ko, Al);
        g2l16(Bg0 + ko, Bl0);
        g2l16(Bg1 + ko, Bl1);
        __syncthreads();
        bf16x8 aF[2], bF[4];
#pragma unroll
        for (int mi = 0; mi < 2; mi++) aF[mi] = *(const bf16x8*)&As[(wm + mi * 16 + l16) * 32 + soct];
#pragma unroll
        for (int ni = 0; ni < 4; ni++) bF[ni] = *(const bf16x8*)&Bs[(wn + ni * 16 + l16) * 32 + soct];
#pragma unroll
        for (int mi = 0; mi < 2; mi++)
#pragma unroll
            for (int ni = 0; ni < 4; ni++)
                acc[mi][ni] = __builtin_amdgcn_mfma_f32_16x16x32_bf16(aF[mi], bF[ni], acc[mi][ni], 0, 0, 0);
        __syncthreads();
    }

#pragma unroll
    for (int ni = 0; ni < 4; ni++) {
        int col = n0 + wn + ni * 16 + l16;
        float bb;
        if (MODE == 0) bb = (col < 768) ? bias0[col] : ((col < 1536) ? bias1[col - 768] : bias2[col - 1536]);
        else if (MODE == 1) bb = (blockIdx.z == 0) ? bias0[col] : 0.0f;
        else bb = bias0[col];
#pragma unroll
        for (int mi = 0; mi < 2; mi++) {
            int row = m0 + wm + mi * 16 + qd * 4;
#pragma unroll
            for (int r = 0; r < 4; r++) {
                float v = acc[mi][ni][r] + bb;
                if (MODE == 0) {
                    if (col < 768) v *= 0.125f;  // 1/sqrt(64)
                    outB[(size_t)(row + r) * N + col] = __float2bfloat16(v);
                } else if (MODE == 1) {
                    outF[(size_t)blockIdx.z * M * N + (size_t)(row + r) * N + col] = v;
                } else {
                    v = fmaxf(v, 0.0f);
                    outB[(size_t)(row + r) * N + col] = __float2bfloat16(v);
                }
            }
        }
    }
}

// ---------------- MFMA windowed attention ----------------
#define KT 288
#define KSTR 72   // Ks row stride (16B-aligned, hashes to 2-way banks)
#define VSTR 296  // Vt / Ps row stride
__global__ __launch_bounds__(256, 2) void attn_kernel(const bf16* __restrict__ qkv,
                                                      const int* __restrict__ tokens,
                                                      const float* __restrict__ relb,
                                                      bf16* __restrict__ out) {
    const int q0 = blockIdx.x * 32;
    const int h = blockIdx.y;
    const int t = threadIdx.x;
    const int lane = t & 63, w = t >> 6;
    const int l16 = lane & 15, qd = lane >> 4;
    const int klo = max(0, q0 - WIN);

    __shared__ __align__(16) unsigned short KsPs[KT * KSTR];
    __shared__ __align__(16) unsigned short VtS[64 * VSTR];
    __shared__ float rbS[260];
    __shared__ float wmaxS[4][32];
    __shared__ float wsumS[4][32];
    __shared__ char kmS[KT];

    const unsigned short* qkvu = (const unsigned short*)qkv;

#pragma unroll
    for (int j = 0; j < 9; j++) {
        int i = j * 256 + t;
        int key = i >> 3, oct = i & 7;
        int ksrc = min(klo + key, S - 1);
        *(u16x8*)&KsPs[key * KSTR + oct * 8] =
            *(const u16x8*)(qkvu + (size_t)ksrc * 2304 + 768 + h * 64 + oct * 8);
    }
#pragma unroll
    for (int j = 0; j < 9; j++) {
        int i = j * 256 + t;
        int oct = i / KT;
        int key = i - oct * KT;
        int ksrc = min(klo + key, S - 1);
        u16x8 v = *(const u16x8*)(qkvu + (size_t)ksrc * 2304 + 1536 + h * 64 + oct * 8);
#pragma unroll
        for (int u = 0; u < 8; u++) VtS[(oct * 8 + u) * VSTR + key] = v[u];
    }
    for (int idx = t; idx < 260; idx += 256) {
        int dd = idx - 129;
        float bv = -1e30f;
        if (dd >= -128 && dd <= 128) {
            int ni = dd, ret = 0;
            if (ni < 0) { ret = 16; ni = -ni; }
            int val;
            if (ni < 8) val = ni;
            else {
                int m;
                if (ni < 12) m = 0; else if (ni < 16) m = 1; else if (ni < 23) m = 2;
                else if (ni < 32) m = 3; else if (ni < 46) m = 4; else if (ni < 64) m = 5;
                else if (ni < 91) m = 6; else if (ni < 128) m = 7; else m = 8;
                val = 8 + m;
                if (val > 15) val = 15;
            }
            bv = relb[(ret + val) * H + h];
        }
        rbS[idx] = bv;
    }
    for (int idx = t; idx < KT; idx += 256) {
        int key = klo + idx;
        kmS[idx] = (key < S && tokens[key] != PADIDX) ? 0 : 1;
    }
    __syncthreads();

    bf16x8 Qf[2][2];
#pragma unroll
    for (int qt = 0; qt < 2; qt++)
#pragma unroll
        for (int ko = 0; ko < 2; ko++)
            Qf[qt][ko] = *(const bf16x8*)(qkvu + (size_t)(q0 + qt * 16 + l16) * 2304 + h * 64 + ko * 32 + qd * 8);

    f32x4 acc[2][5] = {};
#pragma unroll
    for (int j = 0; j < 5; j++) {
        int kt = w + 4 * j;
        if (kt < 18) {
            bf16x8 b0 = *(const bf16x8*)&KsPs[(kt * 16 + l16) * KSTR + qd * 8];
            bf16x8 b1 = *(const bf16x8*)&KsPs[(kt * 16 + l16) * KSTR + 32 + qd * 8];
#pragma unroll
            for (int qt = 0; qt < 2; qt++) {
                acc[qt][j] = __builtin_amdgcn_mfma_f32_16x16x32_bf16(Qf[qt][0], b0, acc[qt][j], 0, 0, 0);
                acc[qt][j] = __builtin_amdgcn_mfma_f32_16x16x32_bf16(Qf[qt][1], b1, acc[qt][j], 0, 0, 0);
            }
        }
    }

    float rmax[2][4];
#pragma unroll
    for (int qt = 0; qt < 2; qt++)
#pragma unroll
        for (int r = 0; r < 4; r++) rmax[qt][r] = -3e38f;
    const int qmk = q0 - klo;
#pragma unroll
    for (int j = 0; j < 5; j++) {
        int kt = w + 4 * j;
        if (kt < 18) {
            int kidx = kt * 16 + l16;
            float km = kmS[kidx] ? -1e30f : 0.0f;
#pragma unroll
            for (int qt = 0; qt < 2; qt++)
#pragma unroll
                for (int r = 0; r < 4; r++) {
                    int dd = qmk + qt * 16 + qd * 4 + r - kidx;
                    dd = min(129, max(-129, dd));
                    float sc = acc[qt][j][r] + rbS[dd + 129] + km;
                    acc[qt][j][r] = sc;
                    rmax[qt][r] = fmaxf(rmax[qt][r], sc);
                }
        }
    }
#pragma unroll
    for (int m = 1; m < 16; m <<= 1)
#pragma unroll
        for (int qt = 0; qt < 2; qt++)
#pragma unroll
            for (int r = 0; r < 4; r++)
                rmax[qt][r] = fmaxf(rmax[qt][r], __shfl_xor(rmax[qt][r], m));
    if (l16 == 0) {
#pragma unroll
        for (int qt = 0; qt < 2; qt++)
#pragma unroll
            for (int r = 0; r < 4; r++) wmaxS[w][qt * 16 + qd * 4 + r] = rmax[qt][r];
    }
    __syncthreads();

    float gmax[2][4];
#pragma unroll
    for (int qt = 0; qt < 2; qt++)
#pragma unroll
        for (int r = 0; r < 4; r++) {
            int row = qt * 16 + qd * 4 + r;
            gmax[qt][r] = fmaxf(fmaxf(wmaxS[0][row], wmaxS[1][row]), fmaxf(wmaxS[2][row], wmaxS[3][row]));
        }

    float lsum[2][4] = {};
#pragma unroll
    for (int j = 0; j < 5; j++) {
        int kt = w + 4 * j;
        if (kt < 18) {
#pragma unroll
            for (int qt = 0; qt < 2; qt++)
#pragma unroll
                for (int r = 0; r < 4; r++) {
                    float p = __expf(acc[qt][j][r] - gmax[qt][r]);
                    lsum[qt][r] += p;
                    KsPs[(qt * 16 + qd * 4 + r) * VSTR + kt * 16 + l16] = f2bfu(p);
                }
        }
    }
#pragma unroll
    for (int m = 1; m < 16; m <<= 1)
#pragma unroll
        for (int qt = 0; qt < 2; qt++)
#pragma unroll
            for (int r = 0; r < 4; r++) lsum[qt][r] += __shfl_xor(lsum[qt][r], m);
    if (l16 == 0) {
#pragma unroll
        for (int qt = 0; qt < 2; qt++)
#pragma unroll
            for (int r = 0; r < 4; r++) wsumS[w][qt * 16 + qd * 4 + r] = lsum[qt][r];
    }
    __syncthreads();

    {
        int qt = w & 1, dt0 = (w >> 1) * 2;
        f32x4 o0 = {}, o1 = {};
#pragma unroll
        for (int kk = 0; kk < 9; kk++) {
            bf16x8 aP = *(const bf16x8*)&KsPs[(qt * 16 + l16) * VSTR + kk * 32 + qd * 8];
            bf16x8 v0 = *(const bf16x8*)&VtS[(dt0 * 16 + l16) * VSTR + kk * 32 + qd * 8];
            bf16x8 v1 = *(const bf16x8*)&VtS[((dt0 + 1) * 16 + l16) * VSTR + kk * 32 + qd * 8];
            o0 = __builtin_amdgcn_mfma_f32_16x16x32_bf16(aP, v0, o0, 0, 0, 0);
            o1 = __builtin_amdgcn_mfma_f32_16x16x32_bf16(aP, v1, o1, 0, 0, 0);
        }
#pragma unroll
        for (int r = 0; r < 4; r++) {
            int row = qt * 16 + qd * 4 + r;
            float ts = wsumS[0][row] + wsumS[1][row] + wsumS[2][row] + wsumS[3][row];
            float inv = 1.0f / ts;
            size_t obase = (size_t)(q0 + row) * D + h * 64;
            out[obase + dt0 * 16 + l16] = __float2bfloat16(o0[r] * inv);
            out[obase + (dt0 + 1) * 16 + l16] = __float2bfloat16(o1[r] * inv);
        }
    }
}

// ---------------- residual + NP split-K partials + layernorm ----------------
template <int NP>
__global__ __launch_bounds__(256) void ln_kernel(const float* __restrict__ x, const float* __restrict__ parts,
                                                 const float* __restrict__ sc, const float* __restrict__ bi,
                                                 float* __restrict__ out, bf16* __restrict__ out_bf) {
    int row = blockIdx.x, t = threadIdx.x;
    float v[3];
    float lsum = 0.0f, lsq = 0.0f;
#pragma unroll
    for (int i = 0; i < 3; i++) {
        int c = t + i * 256;
        size_t idx = (size_t)row * D + c;
        float val = x[idx];
#pragma unroll
        for (int p = 0; p < NP; p++) val += parts[(size_t)p * S * D + idx];
        v[i] = val; lsum += val; lsq += val * val;
    }
#pragma unroll
    for (int off = 32; off; off >>= 1) { lsum += __shfl_down(lsum, off); lsq += __shfl_down(lsq, off); }
    __shared__ float s1[4], s2[4];
    if ((t & 63) == 0) { s1[t >> 6] = lsum; s2[t >> 6] = lsq; }
    __syncthreads();
    float tot = s1[0] + s1[1] + s1[2] + s1[3];
    float tot2 = s2[0] + s2[1] + s2[2] + s2[3];
    float mean = tot * (1.0f / 768.0f);
    float var = tot2 * (1.0f / 768.0f) - mean * mean;
    float rstd = rsqrtf(var + 1e-5f);
#pragma unroll
    for (int i = 0; i < 3; i++) {
        int c = t + i * 256;
        float y = (v[i] - mean) * rstd * sc[c] + bi[c];
        out[(size_t)row * D + c] = y;
        out_bf[(size_t)row * D + c] = __float2bfloat16(y);
    }
}

extern "C" void kernel_launch(void* const* d_in, const int* in_sizes, int n_in,
                              void* d_out, int out_size, void* d_ws, size_t ws_size,
                              hipStream_t stream) {
    const int* tokens = (const int*)d_in[0];
    const int* seg = (const int*)d_in[1];
    const float* emb = (const float*)d_in[2];
    const float* pemb = (const float*)d_in[3];
    const float* semb = (const float*)d_in[4];
    const float* relb = (const float*)d_in[5];
    const float* Wq = (const float*)d_in[6];  const float* bq = (const float*)d_in[7];
    const float* Wk = (const float*)d_in[8];  const float* bk = (const float*)d_in[9];
    const float* Wv = (const float*)d_in[10]; const float* bv = (const float*)d_in[11];
    const float* Wo = (const float*)d_in[12]; const float* bo = (const float*)d_in[13];
    const float* ln1s = (const float*)d_in[14]; const float* ln1b = (const float*)d_in[15];
    const float* W1 = (const float*)d_in[16]; const float* b1 = (const float*)d_in[17];
    const float* W2 = (const float*)d_in[18]; const float* b2 = (const float*)d_in[19];
    const float* ln2s = (const float*)d_in[20]; const float* ln2b = (const float*)d_in[21];

    char* base = (char*)d_ws;
    size_t off = 0;
    auto take = [&](size_t bytes) -> char* {
        char* p = base + off;
        off = (off + bytes + 255) & ~(size_t)255;
        return p;
    };
    int* positions = (int*)take((size_t)S * 4);
    float* h       = (float*)take((size_t)S * D * 4);
    bf16* h_bf     = (bf16*)take((size_t)S * D * 2);
    float* parts   = (float*)take((size_t)4 * S * D * 4);
    bf16* qkv      = (bf16*)take((size_t)S * 2304 * 2);
    bf16* attnO    = (bf16*)take((size_t)S * D * 2);
    bf16* ff1      = (bf16*)take((size_t)S * FF * 2);
    bf16* Wqkv_t   = (bf16*)take((size_t)NL * 2304 * 768 * 2);
    bf16* Wo_t     = (bf16*)take((size_t)NL * 768 * 768 * 2);
    bf16* W1_t     = (bf16*)take((size_t)NL * 3072 * 768 * 2);
    bf16* W2_t     = (bf16*)take((size_t)NL * 768 * 3072 * 2);
    (void)ws_size; (void)n_in; (void)in_sizes;

    positions_kernel<<<1, 256, 0, stream>>>(tokens, positions);
    embed_kernel<<<S, 256, 0, stream>>>(tokens, seg, positions, emb, pemb, semb, h, h_bf);

    transpose_convert<<<dim3(12, 12, NL), 256, 0, stream>>>(Wq, Wqkv_t, 768, 768, 768L * 768, 2304L * 768);
    transpose_convert<<<dim3(12, 12, NL), 256, 0, stream>>>(Wk, Wqkv_t + 768L * 768, 768, 768, 768L * 768, 2304L * 768);
    transpose_convert<<<dim3(12, 12, NL), 256, 0, stream>>>(Wv, Wqkv_t + 1536L * 768, 768, 768, 768L * 768, 2304L * 768);
    transpose_convert<<<dim3(12, 12, NL), 256, 0, stream>>>(Wo, Wo_t, 768, 768, 768L * 768, 768L * 768);
    transpose_convert<<<dim3(12, 48, NL), 256, 0, stream>>>(W1, W1_t, 768, 3072, 768L * 3072, 3072L * 768);
    transpose_convert<<<dim3(48, 12, NL), 256, 0, stream>>>(W2, W2_t, 3072, 768, 3072L * 768, 768L * 3072);

    for (int l = 0; l < NL; l++) {
        gemm64<0><<<dim3(32, 18, 1), 256, 0, stream>>>(h_bf, Wqkv_t + (size_t)l * 2304 * 768,
                                                       bq + l * 768, bk + l * 768, bv + l * 768,
                                                       nullptr, qkv, S, 2304, 768, 768);
        attn_kernel<<<dim3(S / 32, H), 256, 0, stream>>>(qkv, tokens, relb, attnO);
        gemm64<1><<<dim3(32, 6, 2), 256, 0, stream>>>(attnO, Wo_t + (size_t)l * 768 * 768,
                                                      bo + l * 768, nullptr, nullptr,
                                                      parts, nullptr, S, 768, 768, 384);
        ln_kernel<2><<<S, 256, 0, stream>>>(h, parts, ln1s + l * 768, ln1b + l * 768, h, h_bf);
        gemm64<2><<<dim3(32, 24, 1), 256, 0, stream>>>(h_bf, W1_t + (size_t)l * 3072 * 768,
                                                       b1 + l * 3072, nullptr, nullptr,
                                                       nullptr, ff1, S, 3072, 768, 768);
        gemm64<1><<<dim3(32, 6, 4), 256, 0, stream>>>(ff1, W2_t + (size_t)l * 768 * 3072,
                                                      b2 + l * 768, nullptr, nullptr,
                                                      parts, nullptr, S, 768, 3072, 768);
        ln_kernel<4><<<S, 256, 0, stream>>>(h, parts, ln2s + l * 768, ln2b + l * 768, h, h_bf);
    }
    hipMemcpyAsync(d_out, h, (size_t)out_size * 4, hipMemcpyDeviceToDevice, stream);
}